// Round 11
// baseline (259.261 us; speedup 1.0000x reference)
//
#include <hip/hip_runtime.h>
#include <hip/hip_bf16.h>

// Problem constants (fixed by the reference)
#define B_  4
#define T_  2048
#define D_  1024
#define H_  16
#define HD_ 64
#define THREE_D (3 * D_)
#define TWO_D   (2 * D_)

typedef short s16x8 __attribute__((ext_vector_type(8)));   // 8 bf16 (4 VGPRs)
typedef float f32x4 __attribute__((ext_vector_type(4)));   // MFMA C/D frag
typedef unsigned short u16;
typedef unsigned short u16x4 __attribute__((ext_vector_type(4)));
typedef unsigned int u32x2 __attribute__((ext_vector_type(2)));

static __device__ __forceinline__ s16x8 load8(const u16* p) {
    return *reinterpret_cast<const s16x8*>(p);
}
static __device__ __forceinline__ u16 f2bf(float f) {
    __hip_bfloat16 h = __float2bfloat16(f);
    return *reinterpret_cast<u16*>(&h);
}
// truncating pack: (trunc_bf16(hi) << 16) | trunc_bf16(lo), ONE v_perm_b32.
static __device__ __forceinline__ unsigned pktrunc(float lo, float hi) {
#if __has_builtin(__builtin_amdgcn_perm)
    return __builtin_amdgcn_perm(__builtin_bit_cast(unsigned, hi),
                                 __builtin_bit_cast(unsigned, lo),
                                 0x07060302u);
#else
    return (__builtin_bit_cast(unsigned, hi) & 0xFFFF0000u) |
           (__builtin_bit_cast(unsigned, lo) >> 16);
#endif
}
// RAW-HW exp2: v_exp_f32 (the r8->r9 fix; OCML exp2f is ~15-20 VALU ops).
static __device__ __forceinline__ float fast_exp2(float x) {
#if __has_builtin(__builtin_amdgcn_exp2f)
    return __builtin_amdgcn_exp2f(x);
#else
    float r;
    asm("v_exp_f32 %0, %1" : "=v"(r) : "v"(x));
    return r;
#endif
}

// global -> LDS direct DMA, 16B per lane
static __device__ __forceinline__ void gload_lds16(const u16* g, u16* l) {
#if __has_builtin(__builtin_amdgcn_global_load_lds)
    __builtin_amdgcn_global_load_lds(
        (__attribute__((address_space(1))) void*)g,
        (__attribute__((address_space(3))) void*)l, 16, 0, 0);
#else
    *reinterpret_cast<s16x8*>(l) = load8(g);
#endif
}

// ---------------------------------------------------------------------------
// fp32 -> bf16 convert (RNE), 4 elements/thread, 3 buffers in ONE launch.
// ---------------------------------------------------------------------------
__global__ __launch_bounds__(256) void cvt3_f32_bf16(
    const float* __restrict__ a, u16* __restrict__ oa, int na,
    const float* __restrict__ bsrc, u16* __restrict__ ob, int nb,
    const float* __restrict__ c, u16* __restrict__ oc, int nc)
{
    int i = (blockIdx.x * 256 + threadIdx.x) * 4;
    const float* s; u16* d;
    if (i < na)                { s = a;    d = oa; }
    else if ((i -= na) < nb)   { s = bsrc; d = ob; }
    else if ((i -= nb) < nc)   { s = c;    d = oc; }
    else return;
    const float4 f = *reinterpret_cast<const float4*>(s + i);
    u16x4 r;
    r.x = f2bf(f.x); r.y = f2bf(f.y); r.z = f2bf(f.z); r.w = f2bf(f.w);
    *reinterpret_cast<u16x4*>(d + i) = r;
}

// ---------------------------------------------------------------------------
// QKV GEMM, 256x256 tile / BK=64 / 8 waves (2M x 4N, wave = 128x64) with the
// 8-phase counted-vmcnt schedule. Third attempt; defects of r5/r6 fixed:
//
//  * Phases split along K-HALVES (kh = the two 16x16x32 k-steps of BK=64).
//    Per K-tile, 4 phases: (ks0,mh0)+8 ds_read, (ks0,mh1)+4, (ks1,mh0)+8,
//    (ks1,mh1)+4; 16 MFMA each; B-frags persist across the mh pair.
//  * Within-phase order (true template order): ds_read issue -> stage issue
//    (2 gload_lds = 1 half-tile) -> [vmcnt] -> s_barrier -> lgkmcnt(0) ->
//    setprio(1) -> 16 MFMA -> setprio(0) -> s_barrier.
//  * vmcnt(4) TWICE per K-tile (phases 2,4) -- not every phase (r6's killer
//    stall). Audit (steady state, 2 loads/phase, stage order per tile t+1:
//    ph1 Akh0, ph2 Bkh0, ph3 Akh1, ph4 Bkh1):
//      ph2 vmcnt(4): outstanding = {Bkh0(t+1),Akh0(t+1),Bkh1(t),Akh1(t)}=8
//        -> waits kh1(t) landed (needed ph3); leaves kh0(t+1) in flight.
//      ph4 vmcnt(4): outstanding = 4 halves of t+1 = 8 -> waits kh0(t+1)
//        landed (needed (t+1).ph1); leaves kh1(t+1). Invariant closed.
//    Every wait targets loads issued >=2 phases (~400+ cyc) earlier.
//    Last tile re-stages tile 0 (never read) to keep counts uniform.
//  * LDS swizzle = r10's measured-ZERO-conflict pattern: [row][32K] halves,
//    stored chunk = logical ^ ((row>>1)&3), applied to the pre-swizzled
//    GLOBAL source column (DMA dest lane-linear) and the ds_read chunk.
//  * vmcnt(0) before exit: DMA into LDS of an exited workgroup would
//    corrupt the next block's LDS allocation.
//  Epilogue: cols [0,1024) Q*qsc, [1024,2048) K -> qk; [2048,3072) V -> vt
//  transposed (identical numerics to gemm_bt128 MODE 1).
// ---------------------------------------------------------------------------
__global__ __launch_bounds__(512, 2) void gemm256p(
    const u16* __restrict__ A, const u16* __restrict__ Bm,
    u16* __restrict__ Cq, u16* __restrict__ vt, float qsc)
{
    // M=8192, N=3072, K=1024, lda=ldb=1024. 384 blocks = 48/XCD (bijective).
    const int mtpc = 4;                        // 48 blocks/XCD / 12 ntiles
    const int xcd = (int)blockIdx.x & 7;
    const int lc  = (int)blockIdx.x >> 3;
    const int nt = lc / mtpc, mt = xcd * mtpc + (lc % mtpc);
    const int m0 = mt << 8, n0 = nt << 8;

    const int tid  = threadIdx.x;
    const int lane = tid & 63;
    const int l15  = lane & 15;
    const int quad = lane >> 4;
    const int wave = tid >> 6;
    const int wm2  = wave >> 2;                // 0..1 : 128-row band
    const int wn4  = wave & 3;                 // 0..3 : 64-col band

    __shared__ u16 Ash[2][2][256 * 32];        // [dbuf][kh][row*32+k] 64 KB
    __shared__ u16 Bsh[2][2][256 * 32];        // 64 KB (128 KB total)

    f32x4 acc[8][4] = {};

    // staging: chunks c = tid (rows 0..127) and tid+512 (rows 128..255);
    // row = c>>2, chunk = c&3; source column pre-swizzled (r10 pattern).
    const int scol = (((tid & 3) ^ ((tid >> 3) & 3)) * 8);
    const u16* Ag = A  + (size_t)(m0 + (tid >> 2)) * D_ + scol;
    const u16* Bg = Bm + (size_t)(n0 + (tid >> 2)) * D_ + scol;

    // read-side swizzle constant (rows are 16*i + l15)
    const int rdo = ((quad ^ ((l15 >> 1) & 3)) * 8);

#define STG(Xg, Xsh, db, kh, kt) do {                                        \
        const size_t off_ = (size_t)(kt) * 64 + (kh) * 32;                   \
        gload_lds16(Xg + off_, &Xsh[db][kh][(size_t)tid * 8]);               \
        gload_lds16(Xg + (size_t)128 * D_ + off_,                            \
                    &Xsh[db][kh][((size_t)tid + 512) * 8]);                  \
    } while (0)

#define RD_A(d, ks, mf) (*reinterpret_cast<const s16x8*>(                    \
        &Ash[d][ks][(wm2 * 128 + (mf) * 16 + l15) * 32 + rdo]))
#define RD_B(d, ks, nf) (*reinterpret_cast<const s16x8*>(                    \
        &Bsh[d][ks][(wn4 * 64 + (nf) * 16 + l15) * 32 + rdo]))

#define PHASE(d, ks, mh, RELB, STGCALL, VM) do {                             \
        s16x8 af[4];                                                         \
        _Pragma("unroll")                                                    \
        for (int f = 0; f < 4; ++f) {                                        \
            af[f] = RD_A(d, ks, (mh) * 4 + f);                               \
            if (RELB) bfr[f] = RD_B(d, ks, f);                               \
        }                                                                    \
        STGCALL;                                                             \
        if (VM) asm volatile("s_waitcnt vmcnt(4)" ::: "memory");             \
        __builtin_amdgcn_s_barrier();                                        \
        asm volatile("s_waitcnt lgkmcnt(0)" ::: "memory");                   \
        __builtin_amdgcn_s_setprio(1);                                       \
        _Pragma("unroll")                                                    \
        for (int f = 0; f < 4; ++f)                                          \
            _Pragma("unroll")                                                \
            for (int nf = 0; nf < 4; ++nf)                                   \
                acc[(mh) * 4 + f][nf] =                                      \
                    __builtin_amdgcn_mfma_f32_16x16x32_bf16(                 \
                        af[f], bfr[nf], acc[(mh) * 4 + f][nf], 0, 0, 0);     \
        __builtin_amdgcn_s_setprio(0);                                       \
        __builtin_amdgcn_s_barrier();                                        \
    } while (0)

    s16x8 bfr[4];
    // prologue: all 4 half-tiles of tile 0; kh0 must land before ph1 reads
    STG(Ag, Ash, 0, 0, 0); STG(Bg, Bsh, 0, 0, 0);
    STG(Ag, Ash, 0, 1, 0); STG(Bg, Bsh, 0, 1, 0);
    asm volatile("s_waitcnt vmcnt(4)" ::: "memory");
    __builtin_amdgcn_s_barrier();

    for (int t = 0; t < 16; ++t) {
        const int d = t & 1, dn = d ^ 1;
        const int ts = (t + 1) & 15;           // wraps: uniform vmcnt counts
        PHASE(d, 0, 0, 1, STG(Ag, Ash, dn, 0, ts), 0);
        PHASE(d, 0, 1, 0, STG(Bg, Bsh, dn, 0, ts), 1);
        PHASE(d, 1, 0, 1, STG(Ag, Ash, dn, 1, ts), 0);
        PHASE(d, 1, 1, 0, STG(Bg, Bsh, dn, 1, ts), 1);
    }
    asm volatile("s_waitcnt vmcnt(0)" ::: "memory");  // drain before exit!
#undef STG
#undef RD_A
#undef RD_B
#undef PHASE

    // Epilogue. C/D layout: row = quad*4 + r, col = l15.
    #pragma unroll
    for (int nf = 0; nf < 4; ++nf) {
        const int col = n0 + wn4 * 64 + nf * 16 + l15;
        if (col < TWO_D) {                   // Q (scaled) or K -> qk buffer
            const float sc = (col < D_) ? qsc : 1.0f;
            #pragma unroll
            for (int mf = 0; mf < 8; ++mf) {
                const int row = m0 + wm2 * 128 + mf * 16 + quad * 4;
                #pragma unroll
                for (int r = 0; r < 4; ++r)
                    Cq[(size_t)(row + r) * TWO_D + col] = f2bf(acc[mf][nf][r] * sc);
            }
        } else {                             // V -> transposed vt, packed b64
            const int vc = col - TWO_D;      // h*64 + f
            #pragma unroll
            for (int mf = 0; mf < 8; ++mf) {
                const int row = m0 + wm2 * 128 + mf * 16 + quad * 4;
                const int bb = row >> 11, tt = row & (T_ - 1);
                u16x4 pk;
                #pragma unroll
                for (int r = 0; r < 4; ++r) pk[r] = f2bf(acc[mf][nf][r]);
                *reinterpret_cast<u16x4*>(
                    vt + ((size_t)(bb * H_ * HD_) + vc) * T_ + tt) = pk;
            }
        }
    }
}

// ---------------------------------------------------------------------------
// m97-style GEMM, BK=64 as two 32-wide panels. C = A @ Bm^T.
// XCD-chunked block swizzle (r8) + zero-conflict LDS chunk swizzle (r10).
// MODE 0: fp32 out + fp32 bias (projection GEMM) -- the only mode launched.
// ---------------------------------------------------------------------------
template<int MODE>
__global__ __launch_bounds__(256) void gemm_bt128(
    const u16* __restrict__ A,
    const u16* __restrict__ Bm,
    void* __restrict__ Cv,
    const float* __restrict__ bias,
    int M, int N, int K, int lda, int ldb, int ldc,
    float qsc, u16* __restrict__ vt)
{
    const int ntiles = N >> 7;
    const int nwg  = (M >> 7) * ntiles;
    const int cpx  = nwg >> 3;            // blocks per XCD chunk
    const int mtpc = cpx / ntiles;        // mt rows per chunk
    const int xcd  = (int)blockIdx.x & 7;
    const int lc   = (int)blockIdx.x >> 3;
    const int nt = lc / mtpc;
    const int mt = xcd * mtpc + (lc % mtpc);
    const int m0 = mt * 128, n0 = nt * 128;
    const int tid  = threadIdx.x;
    const int lane = tid & 63;
    const int l15  = lane & 15;
    const int quad = lane >> 4;
    const int wave = tid >> 6;
    const int wm = (wave >> 1) * 64;   // wave m-offset in tile
    const int wn = (wave & 1) * 64;    // wave n-offset in tile

    __shared__ u16 A_sh[2][128 * 32];  // [panel][row*32 + k], chunk-swizzled
    __shared__ u16 B_sh[2][128 * 32];

    f32x4 acc[4][4] = {};

    const int c0 = tid, c1 = tid + 256;
    const int ar0 = c0 >> 2, as0 = (((c0 & 3) ^ ((c0 >> 3) & 3)) * 8);
    const int ar1 = c1 >> 2, as1 = (((c1 & 3) ^ ((c1 >> 3) & 3)) * 8);
    const u16* Ag0 = A  + (size_t)(m0 + ar0) * lda + as0;
    const u16* Ag1 = A  + (size_t)(m0 + ar1) * lda + as1;
    const u16* Bg0 = Bm + (size_t)(n0 + ar0) * ldb + as0;
    const u16* Bg1 = Bm + (size_t)(n0 + ar1) * ldb + as1;

    const int rsw2 = (l15 >> 1) & 3;
    const int rdo  = ((quad ^ rsw2) * 8);

    for (int k0 = 0; k0 < K; k0 += 64) {
        __syncthreads();
        #pragma unroll
        for (int p = 0; p < 2; ++p) {
            gload_lds16(Ag0 + k0 + p * 32, &A_sh[p][c0 * 8]);
            gload_lds16(Ag1 + k0 + p * 32, &A_sh[p][c1 * 8]);
            gload_lds16(Bg0 + k0 + p * 32, &B_sh[p][c0 * 8]);
            gload_lds16(Bg1 + k0 + p * 32, &B_sh[p][c1 * 8]);
        }
        __syncthreads();

        #pragma unroll
        for (int p = 0; p < 2; ++p) {
            s16x8 a[4], b[4];
            #pragma unroll
            for (int i = 0; i < 4; ++i) {
                a[i] = *reinterpret_cast<const s16x8*>(&A_sh[p][(wm + i * 16 + l15) * 32 + rdo]);
                b[i] = *reinterpret_cast<const s16x8*>(&B_sh[p][(wn + i * 16 + l15) * 32 + rdo]);
            }
            #pragma unroll
            for (int mi = 0; mi < 4; ++mi)
                #pragma unroll
                for (int ni = 0; ni < 4; ++ni)
                    acc[mi][ni] = __builtin_amdgcn_mfma_f32_16x16x32_bf16(
                        a[mi], b[ni], acc[mi][ni], 0, 0, 0);
        }
    }

    #pragma unroll
    for (int ni = 0; ni < 4; ++ni) {
        const int col = n0 + wn + ni * 16 + l15;
        if (MODE == 0) {
            const float bv = bias ? bias[col] : 0.0f;
            #pragma unroll
            for (int mi = 0; mi < 4; ++mi) {
                const int row = m0 + wm + mi * 16 + quad * 4;
                #pragma unroll
                for (int r = 0; r < 4; ++r)
                    ((float*)Cv)[(size_t)(row + r) * ldc + col] = acc[mi][ni][r] + bv;
            }
        } else {
            if (col < TWO_D) {
                const float sc = (col < D_) ? qsc : 1.0f;
                #pragma unroll
                for (int mi = 0; mi < 4; ++mi) {
                    const int row = m0 + wm + mi * 16 + quad * 4;
                    #pragma unroll
                    for (int r = 0; r < 4; ++r)
                        ((u16*)Cv)[(size_t)(row + r) * ldc + col] = f2bf(acc[mi][ni][r] * sc);
                }
            } else {
                const int vc = col - TWO_D;
                #pragma unroll
                for (int mi = 0; mi < 4; ++mi) {
                    const int row = m0 + wm + mi * 16 + quad * 4;
                    const int bb = row >> 11, t = row & (T_ - 1);
                    u16x4 pk;
                    #pragma unroll
                    for (int r = 0; r < 4; ++r) pk[r] = f2bf(acc[mi][ni][r]);
                    *reinterpret_cast<u16x4*>(
                        vt + ((size_t)(bb * H_ * HD_) + vc) * T_ + t) = pk;
                }
            }
        }
    }
}

// ---------------------------------------------------------------------------
// Causal flash attention v6x (r9/r10, proven): fast_exp2 + pktrunc P-pack;
// 4 waves x 32 q-rows, KV-tile 64, K/V in [64][64] LDS with 3-bit XOR
// involution (write+read), register prefetch, S^T via mfma(A=kf,B=qf),
// b64 P writes (stride-72 P_lds), ones-MFMA rowsum, qmap load balance.
// ---------------------------------------------------------------------------
__global__ __launch_bounds__(256) void flash_attn6x(
    const u16* __restrict__ qk, const u16* __restrict__ vt,
    u16* __restrict__ out)   // [B*T, D] bf16
{
    const int cls = blockIdx.x >> 6;          // 0..15
    const int bh  = blockIdx.x & 63;
    const int qmap[16] = {15,14,13,12, 8,9,10,11, 7,6,5,4, 0,1,2,3};
    const int qt = qmap[cls];
    const int h = bh & 15, b = bh >> 4;
    const int q0 = qt * 128;

    __shared__ u16 K_lds[64 * 64];         // [key][feat], chunk^=(row&7)
    __shared__ u16 V_lds[64 * 64];         // [feat][key], chunk^=(row&7)
    __shared__ u16 P_lds[4 * 32 * 72];     // per-wave [qrow][key], stride 72

    const int tid = threadIdx.x;
    const int wave = tid >> 6, lane = tid & 63;
    const int l15 = lane & 15, quad = lane >> 4;
    u16* Pw = P_lds + wave * (32 * 72);

    const int w0 = q0 + wave * 32;         // wave's first q-row

    // Q fragments: 2 m-tiles x 2 k-steps (pre-scaled by cs in GEMM1)
    s16x8 qf[2][2];
    #pragma unroll
    for (int mi = 0; mi < 2; ++mi) {
        const size_t rowQ = (size_t)(b * T_ + w0 + mi * 16 + l15) * TWO_D + h * HD_;
        qf[mi][0] = load8(qk + rowQ + quad * 8);
        qf[mi][1] = load8(qk + rowQ + 32 + quad * 8);
    }

    f32x4 o[2][4] = {};
    f32x4 osum[2] = {};

    s16x8 ones;
    #pragma unroll
    for (int j = 0; j < 8; ++j) ones[j] = (short)0x3F80;   // bf16 1.0

    const int r0 = tid >> 3;               // 0..31
    const int s0 = (tid & 7) * 8;          // u16 offset of 16B chunk (global)
    const int wsw = (((tid & 7) ^ (r0 & 7)) * 8);   // swizzled LDS chunk
    const u16* Kg0 = qk + (size_t)(b * T_ + r0)      * TWO_D + D_ + h * HD_ + s0;
    const u16* Kg1 = qk + (size_t)(b * T_ + r0 + 32) * TWO_D + D_ + h * HD_ + s0;
    const u16* Vg0 = vt + (size_t)(bh * HD_ + r0)      * T_ + s0;
    const u16* Vg1 = vt + (size_t)(bh * HD_ + r0 + 32) * T_ + s0;

    // prefetch tile 0
    s16x8 pk0 = load8(Kg0);
    s16x8 pk1 = load8(Kg1);
    s16x8 pv0 = load8(Vg0);
    s16x8 pv1 = load8(Vg1);

    const int rsw = l15 & 7;

    const int nkt = 2 * qt + 2;
    for (int kt = 0; kt < nkt; ++kt) {
        const int kbase = kt * 64;
        __syncthreads();
        *reinterpret_cast<s16x8*>(&K_lds[r0 * 64 + wsw])        = pk0;
        *reinterpret_cast<s16x8*>(&K_lds[(r0 + 32) * 64 + wsw]) = pk1;
        *reinterpret_cast<s16x8*>(&V_lds[r0 * 64 + wsw])        = pv0;
        *reinterpret_cast<s16x8*>(&V_lds[(r0 + 32) * 64 + wsw]) = pv1;
        __syncthreads();

        if (kt + 1 < nkt) {
            const int nb = kbase + 64;
            pk0 = load8(Kg0 + (size_t)nb * TWO_D);
            pk1 = load8(Kg1 + (size_t)nb * TWO_D);
            pv0 = load8(Vg0 + nb);
            pv1 = load8(Vg1 + nb);
        }

        if (kbase <= w0 + 31) {
            f32x4 st[2][4];
            #pragma unroll
            for (int n = 0; n < 4; ++n) {
                const s16x8 kf0 = *reinterpret_cast<const s16x8*>(
                    &K_lds[(n * 16 + l15) * 64 + ((quad ^ rsw) * 8)]);
                const s16x8 kf1 = *reinterpret_cast<const s16x8*>(
                    &K_lds[(n * 16 + l15) * 64 + (((quad ^ 4) ^ rsw) * 8)]);
                #pragma unroll
                for (int mi = 0; mi < 2; ++mi) {
                    f32x4 t = {};
                    t = __builtin_amdgcn_mfma_f32_16x16x32_bf16(kf0, qf[mi][0], t, 0, 0, 0);
                    t = __builtin_amdgcn_mfma_f32_16x16x32_bf16(kf1, qf[mi][1], t, 0, 0, 0);
                    st[mi][n] = t;
                }
            }

            const bool diag = (kbase + 63 > w0);
            #pragma unroll
            for (int mi = 0; mi < 2; ++mi) {
                const int qr = w0 + mi * 16 + l15;
                #pragma unroll
                for (int n = 0; n < 4; ++n) {
                    const int kb = kbase + n * 16 + quad * 4;
                    float e0 = fast_exp2(st[mi][n][0]);
                    float e1 = fast_exp2(st[mi][n][1]);
                    float e2 = fast_exp2(st[mi][n][2]);
                    float e3 = fast_exp2(st[mi][n][3]);
                    if (diag) {
                        if (kb + 0 > qr) e0 = 0.0f;
                        if (kb + 1 > qr) e1 = 0.0f;
                        if (kb + 2 > qr) e2 = 0.0f;
                        if (kb + 3 > qr) e3 = 0.0f;
                    }
                    u32x2 w; w.x = pktrunc(e0, e1); w.y = pktrunc(e2, e3);
                    *reinterpret_cast<u32x2*>(
                        &Pw[(mi * 16 + l15) * 72 + n * 16 + quad * 4]) = w;
                }
            }

            #pragma unroll
            for (int ks = 0; ks < 2; ++ks) {
                s16x8 pa[2];
                #pragma unroll
                for (int mi = 0; mi < 2; ++mi) {
                    pa[mi] = *reinterpret_cast<const s16x8*>(
                        &Pw[(mi * 16 + l15) * 72 + ks * 32 + quad * 8]);
                    osum[mi] = __builtin_amdgcn_mfma_f32_16x16x32_bf16(
                        pa[mi], ones, osum[mi], 0, 0, 0);
                }
                #pragma unroll
                for (int n4 = 0; n4 < 4; ++n4) {
                    const s16x8 vb = *reinterpret_cast<const s16x8*>(
                        &V_lds[(n4 * 16 + l15) * 64 + (((ks * 4 + quad) ^ rsw) * 8)]);
                    #pragma unroll
                    for (int mi = 0; mi < 2; ++mi)
                        o[mi][n4] = __builtin_amdgcn_mfma_f32_16x16x32_bf16(
                            pa[mi], vb, o[mi][n4], 0, 0, 0);
                }
            }
        }
    }

    #pragma unroll
    for (int mi = 0; mi < 2; ++mi)
        #pragma unroll
        for (int r = 0; r < 4; ++r) {
            const float inv = 1.0f / osum[mi][r];
            const size_t rowO = (size_t)(b * T_ + w0 + mi * 16 + quad * 4 + r) * D_ + h * HD_;
            #pragma unroll
            for (int n4 = 0; n4 < 4; ++n4)
                out[rowO + n4 * 16 + l15] = f2bf(o[mi][n4][r] * inv);
        }
}

// ---------------------------------------------------------------------------
extern "C" void kernel_launch(void* const* d_in, const int* in_sizes, int n_in,
                              void* d_out, int out_size, void* d_ws, size_t ws_size,
                              hipStream_t stream)
{
    const float* x     = (const float*)d_in[0];  // [B,T,D]  fp32
    const float* Wqkv  = (const float*)d_in[1];  // [3D,D]   fp32
    const float* Wproj = (const float*)d_in[2];  // [D,D]    fp32
    const float* bproj = (const float*)d_in[3];  // [D]      fp32
    float* out = (float*)d_out;                  // [B,T,D]  fp32

    const int M = B_ * T_;
    const float cs = 0.18033688011f;             // (1/sqrt(64)) * log2(e)

    // Workspace (bf16 = u16). Total 88 MB, no aliasing.
    u16* xb    = (u16*)d_ws;                              // [M, D]       16 MB
    u16* wqkvb = xb    + (size_t)M * D_;                  // [3D, D]       6 MB
    u16* wprob = wqkvb + (size_t)THREE_D * D_;            // [D, D]        2 MB
    u16* qk    = wprob + (size_t)D_ * D_;                 // [M, 2D]      32 MB
    u16* vtb   = qk    + (size_t)M * TWO_D;               // [B*H*64, T]  16 MB
    u16* attn  = vtb   + (size_t)B_ * H_ * HD_ * T_;      // [M, D]       16 MB

    // 0) fp32 -> bf16 converts (single launch, 3 segments)
    {
        const int na = M * D_, nb = THREE_D * D_, nc = D_ * D_;
        const int total = na + nb + nc;
        cvt3_f32_bf16<<<dim3((total / 4 + 255) / 256), 256, 0, stream>>>(
            x, xb, na, Wqkv, wqkvb, nb, Wproj, wprob, nc);
    }

    // 1) qkv GEMM (256^2 8-phase counted-vmcnt): Q*cs, K -> qk; V -> vt
    gemm256p<<<dim3((M / 256) * (THREE_D / 256)), 512, 0, stream>>>(
        xb, wqkvb, qk, vtb, cs);

    // 2) causal flash attention (bf16 out)
    flash_attn6x<<<dim3(B_ * H_ * (T_ / 128)), 256, 0, stream>>>(qk, vtb, attn);

    // 3) out = attn @ Wproj^T + bproj   (fp32 out)
    gemm_bt128<0><<<dim3((M / 128) * (D_ / 128)), 256, 0, stream>>>(
        attn, wprob, out, bproj, M, D_, D_, D_, D_, D_, 1.0f, nullptr);
}